// Round 2
// baseline (207.373 us; speedup 1.0000x reference)
//
#include <hip/hip_runtime.h>

// InternalInteraction: out[b,j,d] = sum_i [ relu((x_i*x_j)@W1^T + b1) @ W2^T + b2 ]
// Factor the i-sum through the (linear) second layer:
//   hsum[b,j,h] = sum_i relu(...), out[b,j,:] = hsum @ W2^T + 16*b2
// B=2048, A=16, D=128, H=512.
// STORAGE: all tensors are fp32 (values pre-rounded to bf16 precision by the
// harness). Round 1 read them as bf16 -> NaN. We load fp32, convert to bf16
// fragments (lossless) for MFMA, and store fp32.

#define BATCH 2048
#define AA 16
#define DD 128
#define HH 512

typedef __bf16 bf16;
typedef bf16  bf16x8 __attribute__((ext_vector_type(8)));
typedef float f32x4  __attribute__((ext_vector_type(4)));

__device__ inline f32x4 splat4(float v) { f32x4 r = {v, v, v, v}; return r; }

__device__ inline bf16x8 cvt2(const f32x4& lo, const f32x4& hi) {
    bf16x8 r;
    r[0] = (bf16)lo[0]; r[1] = (bf16)lo[1]; r[2] = (bf16)lo[2]; r[3] = (bf16)lo[3];
    r[4] = (bf16)hi[0]; r[5] = (bf16)hi[1]; r[6] = (bf16)hi[2]; r[7] = (bf16)hi[3];
    return r;
}

// One block per batch element b. 256 threads = 4 waves.
// Wave w owns H columns [w*128, w*128+128) for GEMM1 and D columns
// [w*32, w*32+32) for GEMM2.
__global__ __launch_bounds__(256, 2)
void interact_kernel(const float* __restrict__ x,   // [B, A, D] fp32
                     const float* __restrict__ W1,  // [H, D]
                     const float* __restrict__ b1,  // [H]
                     const float* __restrict__ W2,  // [D, H]
                     const float* __restrict__ b2,  // [D]
                     float* __restrict__ out)       // [B, A, D] fp32
{
    // bf16 LDS tiles; +8 pad keeps 16B alignment and breaks pow-2 stride.
    __shared__ bf16 xs[16][DD + 8];
    __shared__ bf16 hs[16][HH + 8];

    const int b    = blockIdx.x;
    const int tid  = threadIdx.x;
    const int wave = tid >> 6;
    const int lane = tid & 63;
    const int quad = lane >> 4;   // 0..3
    const int col  = lane & 15;   // 0..15

    // ---- stage x_b into LDS as bf16: 2048 elems, 8 per thread ----
    {
        int row = tid >> 4;          // 0..15
        int d0  = (tid & 15) * 8;    // 0..120
        const float* src = x + (size_t)b * (AA * DD) + row * DD + d0;
        f32x4 lo = *(const f32x4*)(src);
        f32x4 hi = *(const f32x4*)(src + 4);
        *(bf16x8*)(&xs[row][d0]) = cvt2(lo, hi);
    }

    // ---- W1 fragments, persistent in VGPRs (128 regs) ----
    // MFMA B-operand layout: lane holds B[k = quad*8+e][n = lane&15],
    // i.e. 8 contiguous k from a [N,K] row-major array. W1 is [H,D] = [n][k].
    bf16x8 w1f[8][4];
    float  b1f[8];
#pragma unroll
    for (int n = 0; n < 8; ++n) {
        int h  = wave * 128 + n * 16 + col;
        b1f[n] = b1[h];
#pragma unroll
        for (int kk = 0; kk < 4; ++kk) {
            const float* src = W1 + h * DD + kk * 32 + quad * 8;
            f32x4 lo = *(const f32x4*)(src);
            f32x4 hi = *(const f32x4*)(src + 4);
            w1f[n][kk] = cvt2(lo, hi);
        }
    }

    f32x4 hsum[8];
#pragma unroll
    for (int n = 0; n < 8; ++n) hsum[n] = splat4(0.f);

    __syncthreads();

    // ---- i-loop: GEMM1 tile (M=16 j's, N=128/wave, K=128) + relu + accum ----
    for (int i = 0; i < 16; ++i) {
        // A-operand: lane holds A[m = lane&15][k = quad*8+e];
        // A[j][d] = x_j[d] * x_i[d]. (xs[i] read is quad-uniform -> broadcast.)
        bf16x8 af[4];
#pragma unroll
        for (int kk = 0; kk < 4; ++kk) {
            int d0 = kk * 32 + quad * 8;
            bf16x8 xj = *(bf16x8*)(&xs[col][d0]);
            bf16x8 xi = *(bf16x8*)(&xs[i][d0]);
#pragma unroll
            for (int e = 0; e < 8; ++e)
                af[kk][e] = (bf16)((float)xj[e] * (float)xi[e]);
        }

        // acc seeded with b1.
        f32x4 acc[8];
#pragma unroll
        for (int n = 0; n < 8; ++n) acc[n] = splat4(b1f[n]);

#pragma unroll
        for (int kk = 0; kk < 4; ++kk)
#pragma unroll
            for (int n = 0; n < 8; ++n)
                acc[n] = __builtin_amdgcn_mfma_f32_16x16x32_bf16(
                    af[kk], w1f[n][kk], acc[n], 0, 0, 0);

        // relu + accumulate (C/D layout: row j = quad*4+r, col = lane&15)
#pragma unroll
        for (int n = 0; n < 8; ++n)
#pragma unroll
            for (int r = 0; r < 4; ++r)
                hsum[n][r] += fmaxf(acc[n][r], 0.f);
    }

    // ---- hsum -> LDS (bf16) for GEMM2 A-operand re-layout ----
#pragma unroll
    for (int n = 0; n < 8; ++n)
#pragma unroll
        for (int r = 0; r < 4; ++r)
            hs[quad * 4 + r][wave * 128 + n * 16 + col] = (bf16)hsum[n][r];

    __syncthreads();

    // ---- GEMM2: out[j,d] = sum_h hsum[j,h]*W2[d,h] + 16*b2[d] ----
    // M=16 (j), N=32 per wave (d), K=512 (h). W2 is [D,H] = [n][k].
    f32x4 acc2[2];
#pragma unroll
    for (int n2 = 0; n2 < 2; ++n2)
        acc2[n2] = splat4(16.f * b2[wave * 32 + n2 * 16 + col]);

#pragma unroll
    for (int ks = 0; ks < 16; ++ks) {
        int h0 = ks * 32 + quad * 8;
        bf16x8 a2 = *(bf16x8*)(&hs[col][h0]);
#pragma unroll
        for (int n2 = 0; n2 < 2; ++n2) {
            int d = wave * 32 + n2 * 16 + col;
            const float* src = W2 + d * HH + h0;
            f32x4 lo = *(const f32x4*)(src);
            f32x4 hi = *(const f32x4*)(src + 4);
            bf16x8 bw = cvt2(lo, hi);
            acc2[n2] = __builtin_amdgcn_mfma_f32_16x16x32_bf16(
                a2, bw, acc2[n2], 0, 0, 0);
        }
    }

#pragma unroll
    for (int n2 = 0; n2 < 2; ++n2)
#pragma unroll
        for (int r = 0; r < 4; ++r) {
            int j = quad * 4 + r;
            int d = wave * 32 + n2 * 16 + col;
            out[(size_t)b * (AA * DD) + j * DD + d] = acc2[n2][r];
        }
}

extern "C" void kernel_launch(void* const* d_in, const int* in_sizes, int n_in,
                              void* d_out, int out_size, void* d_ws, size_t ws_size,
                              hipStream_t stream)
{
    const float* x  = (const float*)d_in[0];  // [2048,16,128]
    const float* W1 = (const float*)d_in[1];  // [512,128]
    const float* b1 = (const float*)d_in[2];  // [512]
    const float* W2 = (const float*)d_in[3];  // [128,512]
    const float* b2 = (const float*)d_in[4];  // [128]
    float* out = (float*)d_out;

    interact_kernel<<<BATCH, 256, 0, stream>>>(x, W1, b1, W2, b2, out);
}

// Round 3
// 148.234 us; speedup vs baseline: 1.3990x; 1.3990x over previous
//
#include <hip/hip_runtime.h>

// InternalInteraction: out[b,j,d] = sum_i [ relu((x_i*x_j)@W1^T + b1) @ W2^T + b2 ]
// Factored: hsum[b,j,h] = sum_i relu((x_i*x_j)@W1^T + b1); out = hsum@W2^T + 16*b2.
// B=2048, A=16, D=128, H=512. Storage fp32 (bf16-rounded values); MFMA in bf16.
//
// Round-3 structure:
//  - prologue kernel converts W1/W2 to bf16 into d_ws (fragment loads become
//    bare ds-order b128 loads, no cvt chains in the hot kernel)
//  - pair tile (x_i * x_j) built COOPERATIVELY once per i into LDS
//    (double-buffered, 1 barrier/i) instead of 4x redundantly per wave
//  - W1 fragments register-resident per wave (128 VGPRs), acc seeded with b1
//    via the MFMA C operand

#define BATCH 2048
#define AA 16
#define DD 128
#define HH 512

typedef __bf16 bf16;
typedef bf16  bf16x4 __attribute__((ext_vector_type(4)));
typedef bf16  bf16x8 __attribute__((ext_vector_type(8)));
typedef float f32x4  __attribute__((ext_vector_type(4)));

__device__ inline f32x4 splat4(float v) { f32x4 r = {v, v, v, v}; return r; }

// ---- prologue: fp32 -> bf16 weight conversion into d_ws ----
// ws layout: [0, 65536)  = W1b (512x128 row-major bf16)
//            [65536, ..) = W2b (128x512 row-major bf16)
__global__ __launch_bounds__(256, 1)
void convert_weights(const float* __restrict__ W1,
                     const float* __restrict__ W2,
                     bf16* __restrict__ wsb)
{
    int t = blockIdx.x * 256 + threadIdx.x;      // 0..32767, 4 elems each
    f32x4 v = (t < 16384) ? *(const f32x4*)(W1 + 4 * t)
                          : *(const f32x4*)(W2 + 4 * (t - 16384));
    bf16x4 o;
    o[0] = (bf16)v[0]; o[1] = (bf16)v[1]; o[2] = (bf16)v[2]; o[3] = (bf16)v[3];
    *(bf16x4*)(wsb + 4 * t) = o;
}

// One block per batch. 256 threads = 4 waves; wave w owns H cols [w*128, w*128+128).
__global__ __launch_bounds__(256, 2)
void interact_kernel(const float* __restrict__ x,    // [B, A, D] fp32
                     const bf16*  __restrict__ W1b,  // [H, D] bf16 (from ws)
                     const float* __restrict__ b1,   // [H]
                     const bf16*  __restrict__ W2b,  // [D, H] bf16 (from ws)
                     const float* __restrict__ b2,   // [D]
                     float* __restrict__ out)        // [B, A, D] fp32
{
    // Row strides 272B / 1040B = 16B * odd -> b128 accesses land 2-way on
    // banks (free per m136) and stay 16B-aligned.
    __shared__ bf16 xs[16][136];        // x_b, bf16
    __shared__ bf16 ps[2][16][136];     // pair tile, double-buffered
    __shared__ bf16 hs[16][520];        // hsum for GEMM2 re-layout

    const int b    = blockIdx.x;
    const int tid  = threadIdx.x;
    const int wave = tid >> 6;
    const int lane = tid & 63;
    const int quad = lane >> 4;   // 0..3
    const int col  = lane & 15;   // 0..15

    // build-phase coordinates: thread owns (jrow, d0..d0+8)
    const int jrow = tid >> 4;          // 0..15
    const int d0   = (tid & 15) * 8;    // 0..120

    // ---- stage x_b into LDS as bf16 ----
    {
        const float* src = x + (size_t)b * (AA * DD) + jrow * DD + d0;
        f32x4 lo = *(const f32x4*)src;
        f32x4 hi = *(const f32x4*)(src + 4);
        bf16x8 v;
        v[0] = (bf16)lo[0]; v[1] = (bf16)lo[1]; v[2] = (bf16)lo[2]; v[3] = (bf16)lo[3];
        v[4] = (bf16)hi[0]; v[5] = (bf16)hi[1]; v[6] = (bf16)hi[2]; v[7] = (bf16)hi[3];
        *(bf16x8*)(&xs[jrow][d0]) = v;
    }

    // ---- W1 fragments, register-resident (8n x 4kk x 16B = 128 VGPRs) ----
    // B-operand layout: lane holds B[k = quad*8+e + kk*32][n-col], row-major [N,K].
    bf16x8 w1f[8][4];
    float  b1f[8];
#pragma unroll
    for (int n = 0; n < 8; ++n) {
        int h  = wave * 128 + n * 16 + col;
        b1f[n] = b1[h];
#pragma unroll
        for (int kk = 0; kk < 4; ++kk)
            w1f[n][kk] = *(const bf16x8*)(W1b + h * DD + kk * 32 + quad * 8);
    }

    f32x4 hsum[8];
#pragma unroll
    for (int n = 0; n < 8; ++n) hsum[n] = splat4(0.f);

    __syncthreads();

    // xj for the build phase, held as f32 (constant across i)
    float xjf[8];
    {
        bf16x8 xj = *(bf16x8*)(&xs[jrow][d0]);
#pragma unroll
        for (int e = 0; e < 8; ++e) xjf[e] = (float)xj[e];
    }

    // ---- i-loop: cooperative pair build + GEMM1 + relu-accumulate ----
    for (int i = 0; i < 16; ++i) {
        const int p = i & 1;

        // build ps[p][j][d] = bf16(x_j[d] * x_i[d]) — 8 products/thread
        {
            bf16x8 xi = *(bf16x8*)(&xs[i][d0]);
            bf16x8 pr;
#pragma unroll
            for (int e = 0; e < 8; ++e)
                pr[e] = (bf16)(xjf[e] * (float)xi[e]);
            *(bf16x8*)(&ps[p][jrow][d0]) = pr;
        }
        __syncthreads();   // ps[p] ready; prior reads of ps[p^1] already fenced

        // A-operand fragments straight from LDS (no VALU)
        bf16x8 af[4];
#pragma unroll
        for (int kk = 0; kk < 4; ++kk)
            af[kk] = *(bf16x8*)(&ps[p][col][kk * 32 + quad * 8]);

        // acc seeded with b1 through the C operand of the first MFMA
        f32x4 acc[8];
#pragma unroll
        for (int n = 0; n < 8; ++n)
            acc[n] = __builtin_amdgcn_mfma_f32_16x16x32_bf16(
                af[0], w1f[n][0], splat4(b1f[n]), 0, 0, 0);
#pragma unroll
        for (int kk = 1; kk < 4; ++kk)
#pragma unroll
            for (int n = 0; n < 8; ++n)
                acc[n] = __builtin_amdgcn_mfma_f32_16x16x32_bf16(
                    af[kk], w1f[n][kk], acc[n], 0, 0, 0);

        // relu + accumulate (C/D layout: row j = quad*4+r, col = lane&15)
#pragma unroll
        for (int n = 0; n < 8; ++n)
#pragma unroll
            for (int r = 0; r < 4; ++r)
                hsum[n][r] += fmaxf(acc[n][r], 0.f);
    }

    // ---- hsum -> LDS (bf16) for GEMM2 A-operand re-layout ----
#pragma unroll
    for (int n = 0; n < 8; ++n)
#pragma unroll
        for (int r = 0; r < 4; ++r)
            hs[quad * 4 + r][wave * 128 + n * 16 + col] = (bf16)hsum[n][r];

    __syncthreads();

    // ---- GEMM2: out[j,d] = hsum[j,:] @ W2^T + 16*b2 ----
    // M=16 (j), N=32 per wave (d), K=512 (h). W2b is [D,H] row-major.
    f32x4 acc2[2];
#pragma unroll
    for (int n2 = 0; n2 < 2; ++n2)
        acc2[n2] = splat4(16.f * b2[wave * 32 + n2 * 16 + col]);

#pragma unroll
    for (int ks = 0; ks < 16; ++ks) {
        int h0 = ks * 32 + quad * 8;
        bf16x8 a2 = *(bf16x8*)(&hs[col][h0]);
#pragma unroll
        for (int n2 = 0; n2 < 2; ++n2) {
            int d = wave * 32 + n2 * 16 + col;
            bf16x8 bw = *(const bf16x8*)(W2b + d * HH + h0);
            acc2[n2] = __builtin_amdgcn_mfma_f32_16x16x32_bf16(
                a2, bw, acc2[n2], 0, 0, 0);
        }
    }

#pragma unroll
    for (int n2 = 0; n2 < 2; ++n2)
#pragma unroll
        for (int r = 0; r < 4; ++r) {
            int j = quad * 4 + r;
            int d = wave * 32 + n2 * 16 + col;
            out[(size_t)b * (AA * DD) + j * DD + d] = acc2[n2][r];
        }
}

extern "C" void kernel_launch(void* const* d_in, const int* in_sizes, int n_in,
                              void* d_out, int out_size, void* d_ws, size_t ws_size,
                              hipStream_t stream)
{
    const float* x  = (const float*)d_in[0];  // [2048,16,128]
    const float* W1 = (const float*)d_in[1];  // [512,128]
    const float* b1 = (const float*)d_in[2];  // [512]
    const float* W2 = (const float*)d_in[3];  // [128,512]
    const float* b2 = (const float*)d_in[4];  // [128]
    float* out = (float*)d_out;

    bf16* wsb = (bf16*)d_ws;                  // 256 KB used
    convert_weights<<<128, 256, 0, stream>>>(W1, W2, wsb);

    const bf16* W1b = wsb;
    const bf16* W2b = wsb + (size_t)HH * DD;
    interact_kernel<<<BATCH, 256, 0, stream>>>(x, W1b, b1, W2b, b2, out);
}